// Round 8
// baseline (4135.439 us; speedup 1.0000x reference)
//
#include <hip/hip_runtime.h>

#define T_STEPS 8192
#define BATCH   128
#define HID     128
#define NTHR    512               // 8 waves = TWO independent 4-wave engines

typedef float v2f __attribute__((ext_vector_type(2)));

// tanh(z) = 1 - 2/(1+e^{2z}) -- 5 instrs, NaN-free at both infinities.
__device__ __forceinline__ float fast_tanh(float z) {
    float e = __expf(2.0f * z);
    float r = __builtin_amdgcn_rcpf(1.0f + e);
    return fmaf(-2.0f, r, 1.0f);
}

// butterfly sum across a quad (lanes 4q..4q+3): xor1 then xor2 quad_perm.
__device__ __forceinline__ float quad_sum(float x) {
    int t1 = __builtin_amdgcn_update_dpp(0, __builtin_bit_cast(int, x),
                                         0xB1 /*quad_perm [1,0,3,2]*/,
                                         0xf, 0xf, false);
    x += __builtin_bit_cast(float, t1);
    int t2 = __builtin_amdgcn_update_dpp(0, __builtin_bit_cast(int, x),
                                         0x4E /*quad_perm [2,3,0,1]*/,
                                         0xf, 0xf, false);
    return x + __builtin_bit_cast(float, t2);
}

// wave sum of QUAD-UNIFORM values -> total lands in lane 63 (4 DPP adds).
__device__ __forceinline__ float wave_sum_quaduniform_l63(float x) {
#define DPP_ADD(ctrl) do {                                                        \
        int t_ = __builtin_amdgcn_update_dpp(0, __builtin_bit_cast(int, x),       \
                                             (ctrl), 0xf, 0xf, false);            \
        x += __builtin_bit_cast(float, t_); } while (0)
    DPP_ADD(0x114);  // row_shr:4
    DPP_ADD(0x118);  // row_shr:8   -> row sums (one per quad) at row tails
    DPP_ADD(0x142);  // row_bcast:15
    DPP_ADD(0x143);  // row_bcast:31 -> lane 63 holds wave total
#undef DPP_ADD
    return x;
}

__device__ __forceinline__ float bcast_lane(float v, int l) {
    int r = __builtin_amdgcn_readlane(__builtin_bit_cast(int, v), l);
    return __builtin_bit_cast(float, r);
}

#define FORALL16(M) M(0) M(1) M(2) M(3) M(4) M(5) M(6) M(7) \
                    M(8) M(9) M(10) M(11) M(12) M(13) M(14) M(15)

// R22: TWO R18 engines per block. Evidence: R17 (2 elems in ONE wave) was
// exactly 2x -- in-order issue can't overlap a wave's own stalls. R15 (2
// lockstep waves/SIMD) cost only ~240 cyc contention -- co-resident waves
// DO interleave via the HW scheduler. R18's wall is ~850 cyc stall / 190
// cyc issue per wave. So: waves 0-3 = element 2*bid (exact R18), waves
// 4-7 = element 2*bid+1; one shared s_barrier per step serves both groups;
// each SIMD hosts one wave from each group -> group B issues inside group
// A's LDS/DPP/barrier stalls. Per-element arithmetic identical to R18.
__global__ __launch_bounds__(NTHR, 2) void odenet_scan(
    const float* __restrict__ x,
    const float* __restrict__ W1, const float* __restrict__ b1,
    const float* __restrict__ W2, const float* __restrict__ b2,
    const float* __restrict__ W3, const float* __restrict__ b3,
    float* __restrict__ out) {

    const int tid  = threadIdx.x;
    const int w    = tid >> 6;          // wave 0..7
    const int g    = w >> 2;            // element group 0/1
    const int wl   = w & 3;             // wave within group
    const int be   = blockIdx.x * 2 + g;       // this group's batch element
    const int lane = tid & 63;
    const int jg   = lane >> 2;         // j-pair group 0..15
    const int kc   = lane & 3;          // k-chunk [32*kc, 32*kc+32)
    const int j0   = (wl << 5) | (jg << 1);    // owned output units j0, j0+1
    const int j1   = j0 + 1;
    const int kb   = kc << 5;

    // per-wave-private h1: 2 chunks x 68 floats (64 + 4 pad)
    __shared__ __align__(16) float h1buf[8][136];
    __shared__ __align__(16) float dyx[2][8];  // [parity][wave]; group g = quad 4g..4g+3

    // ---- W2 fragments: rows [kb, kb+32) of columns j0 and j1 (16 v2f each) --
    const float* c0p = W2 + j0;         // column j0, row stride HID
    const float* c1p = W2 + j1;
#define DECLW(i) v2f wp##i = {c0p[(kb + 2*(i) + 0) * HID],                        \
                              c0p[(kb + 2*(i) + 1) * HID]};                       \
                 v2f up##i = {c1p[(kb + 2*(i) + 0) * HID],                        \
                              c1p[(kb + 2*(i) + 1) * HID]};
    FORALL16(DECLW)
#undef DECLW
#define PINW(i) asm volatile("" : "+v"(wp##i), "+v"(up##i));
    FORALL16(PINW)
#undef PINW

    // layer-1 weights for the two h1 units this lane computes (k=lane, lane+64)
    float w1xa = W1[lane],      w1ya = W1[HID + lane],      b1a = b1[lane];
    float w1xb = W1[lane + 64], w1yb = W1[HID + lane + 64], b1b = b1[lane + 64];
    float b2j0 = b2[j0], b2j1 = b2[j1];
    float w3j0 = W3[j0], w3j1 = W3[j1], b3v = b3[0];
    asm volatile("" : "+v"(w1xa), "+v"(w1ya), "+v"(b1a),
                      "+v"(w1xb), "+v"(w1yb), "+v"(b1b),
                      "+v"(b2j0), "+v"(b2j1), "+v"(w3j0), "+v"(w3j1), "+v"(b3v));

    float y    = 0.0f;
    float ybuf = 0.0f;                  // all waves capture (symmetric arrival)
    if (wl == 0 && lane == 0) out[be] = 0.0f;   // y_0 = 0

    // ---- x double-buffer: xbuf = current 64-step block, xnext = next ----
    float xbuf  = x[lane * BATCH + be];                // block 0
    int   nb    = 64;                                  // next block base
    float xnext = x[min(nb + lane, T_STEPS - 1) * BATCH + be];
    float xv = bcast_lane(xbuf, 0);
    float ax = fmaf(xv, w1xa, b1a);     // x-side of layer 1 for t=0
    float bx = fmaf(xv, w1xb, b1b);

    // this lane's 32-k chunk: kc=0 -> byte 0, 1 -> 128, 2 -> 272, 3 -> 400
    const float4* h4 = (const float4*)((const char*)&h1buf[w][0] +
                                       ((kc >> 1) * 272 + (kc & 1) * 128));

    for (int t = 0; t < T_STEPS - 1; ++t) {
        const int tm = t & 63;

        // ---- layer 1 (critical path from y: fma+tanh+write only) ----
        float ha = fast_tanh(fmaf(y, w1ya, ax));
        float hb = fast_tanh(fmaf(y, w1yb, bx));
        h1buf[w][lane]      = ha;       // chunk 0 (k = lane)
        h1buf[w][68 + lane] = hb;       // chunk 1 (k = lane+64)

        // ---- layer 2: 8 b128 reads of own 32-k chunk, reused for j0 & j1 ----
        v2f a0 = {0.f, 0.f}, a1 = {0.f, 0.f};   // j0 accumulators
        v2f c0 = {0.f, 0.f}, c1 = {0.f, 0.f};   // j1 accumulators
        {
            float4 q;
#define FMAP(qi, WA, WB, UA, UB) q = h4[qi];                                      \
            { v2f lo = {q.x, q.y}, hi = {q.z, q.w};                               \
              a0 += WA * lo; a1 += WB * hi;                                       \
              c0 += UA * lo; c1 += UB * hi; }
            FMAP(0, wp0 , wp1 , up0 , up1 ) FMAP(1, wp2 , wp3 , up2 , up3 )
            FMAP(2, wp4 , wp5 , up4 , up5 ) FMAP(3, wp6 , wp7 , up6 , up7 )
            FMAP(4, wp8 , wp9 , up8 , up9 ) FMAP(5, wp10, wp11, up10, up11)
            FMAP(6, wp12, wp13, up12, up13) FMAP(7, wp14, wp15, up14, up15)
#undef FMAP
        }
        v2f as_ = a0 + a1;
        v2f cs_ = c0 + c1;

        // ---- k-reduce across the quad (2 DPP levels), tanh, layer 3 ----
        float z0 = quad_sum(as_.x + as_.y);          // full dot for unit j0
        float z1 = quad_sum(cs_.x + cs_.y);          // full dot for unit j1
        float h20 = fast_tanh(z0 + b2j0);
        float h21 = fast_tanh(z1 + b2j1);
        float dyv = fmaf(w3j0, h20, w3j1 * h21);     // quad-uniform
        float dyw = wave_sum_quaduniform_l63(dyv);
        if (lane == 63) dyx[t & 1][w] = dyw;         // direct from lane 63

        // ---- next step's x-side prep (y-independent; fills barrier wait) ----
        const int tmn = (t + 1) & 63;
        if (tmn == 0) {                              // rotate x blocks
            xbuf = xnext;
            nb += 64;
            xnext = x[min(nb + lane, T_STEPS - 1) * BATCH + be];
        }
        float xvn = bcast_lane(xbuf, tmn);
        float axn = fmaf(xvn, w1xa, b1a);
        float bxn = fmaf(xvn, w1xb, b1b);

        // ---- ONE lgkm-only barrier (8 waves) serves BOTH element groups ----
        asm volatile("s_waitcnt lgkmcnt(0)\n\ts_barrier" ::: "memory");

        float4 d = *(const float4*)&dyx[t & 1][g << 2];  // own group's quad
        y += ((d.x + d.y) + (d.z + d.w)) + b3v;      // DT = 1.0

        ybuf = (lane == tm) ? y : ybuf;              // all waves (symmetric)
        if (wl == 0 && tm == 63)
            out[(t - 62 + lane) * BATCH + be] = ybuf;

        ax = axn; bx = bxn;
    }
    // tail: t=8128..8190 captured y_8129..y_8191 in lanes 0..62
    if (wl == 0 && lane < 63)
        out[(T_STEPS - 63 + lane) * BATCH + be] = ybuf;
}

extern "C" void kernel_launch(void* const* d_in, const int* in_sizes, int n_in,
                              void* d_out, int out_size, void* d_ws, size_t ws_size,
                              hipStream_t stream) {
    const float* x  = (const float*)d_in[0];
    const float* W1 = (const float*)d_in[1];
    const float* b1 = (const float*)d_in[2];
    const float* W2 = (const float*)d_in[3];
    const float* b2 = (const float*)d_in[4];
    const float* W3 = (const float*)d_in[5];
    const float* b3 = (const float*)d_in[6];

    odenet_scan<<<dim3(BATCH / 2), dim3(NTHR), 0, stream>>>(
        x, W1, b1, W2, b2, W3, b3, (float*)d_out);
}

// Round 9
// 3893.524 us; speedup vs baseline: 1.0621x; 1.0621x over previous
//
#include <hip/hip_runtime.h>

#define T_STEPS 8192
#define BATCH   128
#define HID     128
#define NTHR    64                // ONE wave: no barrier, no inter-wave exchange

typedef _Float16 h2v  __attribute__((ext_vector_type(2)));
typedef _Float16 h16x8 __attribute__((ext_vector_type(8)));

// tanh(z) = 1 - 2/(1+e^{2z}) -- 5 instrs, NaN-free at both infinities.
__device__ __forceinline__ float fast_tanh(float z) {
    float e = __expf(2.0f * z);
    float r = __builtin_amdgcn_rcpf(1.0f + e);
    return fmaf(-2.0f, r, 1.0f);
}

// full 64-lane wave sum -> total in lane 63 (6 DPP adds, VALU pipe only).
__device__ __forceinline__ float wave_sum_l63(float x) {
#define DPP_ADD(ctrl) do {                                                        \
        int t_ = __builtin_amdgcn_update_dpp(0, __builtin_bit_cast(int, x),       \
                                             (ctrl), 0xf, 0xf, false);            \
        x += __builtin_bit_cast(float, t_); } while (0)
    DPP_ADD(0x111);  // row_shr:1
    DPP_ADD(0x112);  // row_shr:2
    DPP_ADD(0x114);  // row_shr:4
    DPP_ADD(0x118);  // row_shr:8   -> 16-lane row sums at row tails
    DPP_ADD(0x142);  // row_bcast:15
    DPP_ADD(0x143);  // row_bcast:31 -> lane 63 holds wave total
#undef DPP_ADD
    return x;
}

__device__ __forceinline__ float bcast_lane(float v, int l) {
    int r = __builtin_amdgcn_readlane(__builtin_bit_cast(int, v), l);
    return __builtin_bit_cast(float, r);
}

#if __has_builtin(__builtin_amdgcn_fdot2)
#define FDOT2(a, b, c) __builtin_amdgcn_fdot2((a), (b), (c), false)
#else
#define FDOT2(a, b, c) fmaf((float)(a)[0], (float)(b)[0],                         \
                            fmaf((float)(a)[1], (float)(b)[1], (c)))
#endif

#define FORALL64(M) M(0) M(1) M(2) M(3) M(4) M(5) M(6) M(7) \
    M(8) M(9) M(10) M(11) M(12) M(13) M(14) M(15) \
    M(16) M(17) M(18) M(19) M(20) M(21) M(22) M(23) \
    M(24) M(25) M(26) M(27) M(28) M(29) M(30) M(31) \
    M(32) M(33) M(34) M(35) M(36) M(37) M(38) M(39) \
    M(40) M(41) M(42) M(43) M(44) M(45) M(46) M(47) \
    M(48) M(49) M(50) M(51) M(52) M(53) M(54) M(55) \
    M(56) M(57) M(58) M(59) M(60) M(61) M(62) M(63)

// R23: single-wave fp16-dot2 scan. Model (fits R16-R22): R18's 1042 = chain
// ~600 (incl. dy write+barrier+bcast-read ~300, only needed because
// multi-wave) + DS ~140 + issue. R19's single-wave failure = 3 taxes: fp32
// weights forced AGPR copies, 32 fp32 broadcast reads at ~12cyc single-wave
// DS issue, 330-instr VALU. Fix all three with fp16: 128 half2 weight VGPRs
// (fit -> no AGPR), v_dot2_f32_f16 = 2 MAC/instr fp32-acc, h1 fp16 in LDS
// = 16 broadcast b128 reads. Zero barriers; dy = 6-DPP + readlane.
// Precision: h fp16 (random walk ~4e-3) + W fp16 (systematic, damped by
// contractive recurrence ~0.03) at output scale ~16.
__global__ __launch_bounds__(NTHR, 1) void odenet_scan(
    const float* __restrict__ x,
    const float* __restrict__ W1, const float* __restrict__ b1,
    const float* __restrict__ W2, const float* __restrict__ b2,
    const float* __restrict__ W3, const float* __restrict__ b3,
    float* __restrict__ out) {

    const int b    = blockIdx.x;        // batch element
    const int lane = threadIdx.x;       // 0..63, single wave
    const int jA   = lane;              // owned output units
    const int jB   = lane + 64;

    __shared__ _Float16 h1buf[128];     // h1[k] packed fp16, 256 B

    // ---- W2 columns jA, jB as half2 over k-pairs: wa_p={W2[2p][jA],W2[2p+1][jA]}
    const float* cA = W2 + jA;          // column jA, row stride HID
    const float* cB = W2 + jB;
#define DECLA(i) h2v wa##i = {(_Float16)cA[(2*(i)    ) * HID],                    \
                              (_Float16)cA[(2*(i) + 1) * HID]};
#define DECLB(i) h2v wb##i = {(_Float16)cB[(2*(i)    ) * HID],                    \
                              (_Float16)cB[(2*(i) + 1) * HID]};
    FORALL64(DECLA)
    FORALL64(DECLB)
#undef DECLA
#undef DECLB
#define PINA(i) asm volatile("" : "+v"(wa##i));
#define PINB(i) asm volatile("" : "+v"(wb##i));
    FORALL64(PINA)
    FORALL64(PINB)
#undef PINA
#undef PINB

    // layer-1 weights for the two h1 units this lane computes (k=lane, lane+64)
    float w1xa = W1[lane],      w1ya = W1[HID + lane],      b1a = b1[lane];
    float w1xb = W1[lane + 64], w1yb = W1[HID + lane + 64], b1b = b1[lane + 64];
    float b2A = b2[jA], b2B = b2[jB];
    float w3A = W3[jA], w3B = W3[jB], b3v = b3[0];
    asm volatile("" : "+v"(w1xa), "+v"(w1ya), "+v"(b1a),
                      "+v"(w1xb), "+v"(w1yb), "+v"(b1b),
                      "+v"(b2A), "+v"(b2B), "+v"(w3A), "+v"(w3B), "+v"(b3v));

    float y    = 0.0f;
    float ybuf = 0.0f;
    if (lane == 0) out[b] = 0.0f;       // y_0 = 0

    // ---- x double-buffer: xbuf = current 64-step block, xnext = next ----
    float xbuf  = x[lane * BATCH + b];                 // block 0
    int   nb    = 64;                                  // next block base
    float xnext = x[min(nb + lane, T_STEPS - 1) * BATCH + b];
    float xv = bcast_lane(xbuf, 0);
    float ax = fmaf(xv, w1xa, b1a);     // x-side of layer 1 for t=0
    float bx = fmaf(xv, w1xb, b1b);

    const h16x8* h8 = (const h16x8*)h1buf;   // 16 x 16B broadcast reads

    for (int t = 0; t < T_STEPS - 1; ++t) {
        const int tm = t & 63;

        // ---- layer 1 (critical path from y: fma+tanh+cvt+b16 write) ----
        float ha = fast_tanh(fmaf(y, w1ya, ax));
        float hb = fast_tanh(fmaf(y, w1yb, bx));
        h1buf[lane]      = (_Float16)ha;     // k = lane
        h1buf[64 + lane] = (_Float16)hb;     // k = lane + 64

        // ---- layer 2: 16 broadcast b128 reads (lane-uniform addr), 128 dot2 --
        float aA0 = 0.f, aA1 = 0.f, aA2 = 0.f, aA3 = 0.f;   // unit jA
        float aB0 = 0.f, aB1 = 0.f, aB2 = 0.f, aB3 = 0.f;   // unit jB
        {
            h16x8 q;
#define P0 __builtin_shufflevector(q, q, 0, 1)
#define P1 __builtin_shufflevector(q, q, 2, 3)
#define P2 __builtin_shufflevector(q, q, 4, 5)
#define P3 __builtin_shufflevector(q, q, 6, 7)
#define DOT(i, A0, A1, A2, A3, B0, B1, B2, B3) q = h8[i];                         \
            aA0 = FDOT2(P0, A0, aA0); aA1 = FDOT2(P1, A1, aA1);                   \
            aA2 = FDOT2(P2, A2, aA2); aA3 = FDOT2(P3, A3, aA3);                   \
            aB0 = FDOT2(P0, B0, aB0); aB1 = FDOT2(P1, B1, aB1);                   \
            aB2 = FDOT2(P2, B2, aB2); aB3 = FDOT2(P3, B3, aB3);
            DOT( 0, wa0 , wa1 , wa2 , wa3 , wb0 , wb1 , wb2 , wb3 )
            DOT( 1, wa4 , wa5 , wa6 , wa7 , wb4 , wb5 , wb6 , wb7 )
            DOT( 2, wa8 , wa9 , wa10, wa11, wb8 , wb9 , wb10, wb11)
            DOT( 3, wa12, wa13, wa14, wa15, wb12, wb13, wb14, wb15)
            DOT( 4, wa16, wa17, wa18, wa19, wb16, wb17, wb18, wb19)
            DOT( 5, wa20, wa21, wa22, wa23, wb20, wb21, wb22, wb23)
            DOT( 6, wa24, wa25, wa26, wa27, wb24, wb25, wb26, wb27)
            DOT( 7, wa28, wa29, wa30, wa31, wb28, wb29, wb30, wb31)
            DOT( 8, wa32, wa33, wa34, wa35, wb32, wb33, wb34, wb35)
            DOT( 9, wa36, wa37, wa38, wa39, wb36, wb37, wb38, wb39)
            DOT(10, wa40, wa41, wa42, wa43, wb40, wb41, wb42, wb43)
            DOT(11, wa44, wa45, wa46, wa47, wb44, wb45, wb46, wb47)
            DOT(12, wa48, wa49, wa50, wa51, wb48, wb49, wb50, wb51)
            DOT(13, wa52, wa53, wa54, wa55, wb52, wb53, wb54, wb55)
            DOT(14, wa56, wa57, wa58, wa59, wb56, wb57, wb58, wb59)
            DOT(15, wa60, wa61, wa62, wa63, wb60, wb61, wb62, wb63)
#undef DOT
#undef P0
#undef P1
#undef P2
#undef P3
        }

        // ---- next step's x-side prep (no deps; fills dot-phase stalls) ----
        const int tmn = (t + 1) & 63;
        if (tmn == 0) {                              // rotate x blocks
            xbuf = xnext;
            nb += 64;
            xnext = x[min(nb + lane, T_STEPS - 1) * BATCH + b];
        }
        float xvn = bcast_lane(xbuf, tmn);
        float axn = fmaf(xvn, w1xa, b1a);
        float bxn = fmaf(xvn, w1xb, b1b);

        // ---- full dots in-lane: tanh, layer 3, wave reduce (VALU only) ----
        float h2A = fast_tanh(((aA0 + aA1) + (aA2 + aA3)) + b2A);
        float h2B = fast_tanh(((aB0 + aB1) + (aB2 + aB3)) + b2B);
        float dyv = fmaf(w3A, h2A, w3B * h2B);       // per-lane: 2 units
        float dyw = wave_sum_l63(dyv);
        float dy  = bcast_lane(dyw, 63);             // all lanes get total

        y += dy + b3v;                               // DT = 1.0

        ybuf = (lane == tm) ? y : ybuf;
        if (tm == 63)
            out[(t - 62 + lane) * BATCH + b] = ybuf;

        ax = axn; bx = bxn;
    }
    // tail: t=8128..8190 captured y_8129..y_8191 in lanes 0..62
    if (lane < 63)
        out[(T_STEPS - 63 + lane) * BATCH + b] = ybuf;
}

extern "C" void kernel_launch(void* const* d_in, const int* in_sizes, int n_in,
                              void* d_out, int out_size, void* d_ws, size_t ws_size,
                              hipStream_t stream) {
    const float* x  = (const float*)d_in[0];
    const float* W1 = (const float*)d_in[1];
    const float* b1 = (const float*)d_in[2];
    const float* W2 = (const float*)d_in[3];
    const float* b2 = (const float*)d_in[4];
    const float* W3 = (const float*)d_in[5];
    const float* b3 = (const float*)d_in[6];

    odenet_scan<<<dim3(BATCH), dim3(NTHR), 0, stream>>>(
        x, W1, b1, W2, b2, W3, b3, (float*)d_out);
}